// Round 8
// baseline (296.844 us; speedup 1.0000x reference)
//
#include <hip/hip_runtime.h>
#include <math.h>

// PCEN: EMA over time (s=0.025) + (x/(M+eps)^0.98 + 2)^0.5 - 2^0.5
// x: [B=32, T=8192, F=128] f32 -> out same shape f32.
//
// R7 -> R8: SINGLE-PASS chained scan (decoupled lookback, CUB-style).
// Carry into chunk k = sum_{jj=1..6} a^(64(jj-1)) * q[k-jj] (a^384 ~ 6e-5
// truncation; k<=6 exact). Each block: take ticket (atomicAdd => lookback
// targets are always resident-or-retired: deadlock-free under any dispatch
// order), load its 64-t chunk into regs, compute q, publish (threadfence +
// relaxed agent flag), poll 6 predecessor flags (relaxed agent loads +
// acquire threadfence -- agent scope handles non-coherent per-XCD L2),
// compose carry, emit PCEN with nontemporal stores.
// Deletes R7's second kernel: no x re-read, no kernel gap.
// Floor: 134 MB read + 131 MB write ~= 41 us.

#define BB 32
#define TT 8192
#define FF 128
#define CC 64            // chunk timesteps per block
#define KC (TT / CC)     // 128 chunks per chain
#define SUB 16           // timesteps per thread
#define NH  (CC / SUB)   // 4 sub-chunks (one per wave)
#define WW 6             // look-back window in chunks
#define AA 0.975f
#define SS 0.025f

#define NBLK (BB * KC)   // 4096
#define FLAGS_BYTES (NBLK * 4)        // 16 KB
#define TICKET_OFF  FLAGS_BYTES       // int at ws+16384
#define Q_OFF       65536             // q at ws+64KB (2 MB)

using f32x2 = __attribute__((ext_vector_type(2))) float;

constexpr float powf_n(float a, int n) {
    float p = 1.0f;
    for (int i = 0; i < n; ++i) p *= a;
    return p;
}
constexpr float P16 = powf_n(0.975f, 16);   // sub-chunk multiplier
// carry = sum_{jj=1..W} P64^(jj-1) * q[k-jj]
constexpr float WQ[WW] = {
    powf_n(0.975f, 0),   powf_n(0.975f, 64),  powf_n(0.975f, 128),
    powf_n(0.975f, 192), powf_n(0.975f, 256), powf_n(0.975f, 320)
};

__device__ __forceinline__ float pcen_out(float xv, float m) {
    // (m+eps)^(-0.98) via v_log_f32 / v_exp_f32
    float p = __builtin_amdgcn_exp2f(-0.98f * __builtin_amdgcn_logf(m + 1e-6f));
    return sqrtf(fmaf(xv, p, 2.0f)) - 1.41421356237309505f;
}

__global__ __launch_bounds__(256) void pcen_onepass(const float* __restrict__ x,
                                                    float* __restrict__ out,
                                                    float* __restrict__ q,
                                                    int* __restrict__ flags,
                                                    int* __restrict__ ticket) {
    __shared__ f32x2 lds[NH][64];
    __shared__ f32x2 cs[64];
    __shared__ int bid_s;

    const int tid = threadIdx.x;
    const int h   = tid >> 6;            // wave id / sub-chunk, 0..3
    const int f2  = tid & 63;

    if (tid == 0)
        bid_s = __hip_atomic_fetch_add(ticket, 1, __ATOMIC_RELAXED,
                                       __HIP_MEMORY_SCOPE_AGENT);
    __syncthreads();
    const int bid = bid_s;               // virtual block id = b*KC + k
    const int b   = bid >> 7;
    const int k   = bid & (KC - 1);

    const size_t tbase = (size_t)b * TT + (size_t)k * CC + (size_t)h * SUB;
    const f32x2* xp = (const f32x2*)(x + tbase * FF) + f2;
    f32x2*       op = (f32x2*)(out + tbase * FF) + f2;

    f32x2 v[SUB];
    #pragma unroll
    for (int i = 0; i < SUB; ++i) v[i] = xp[(size_t)i * (FF / 2)];

    // sub-aggregate: init-0 EMA over 16 steps (anchored for k==0,h==0)
    float s0, s1;
    if (k == 0 && h == 0) { s0 = v[0][0];      s1 = v[0][1]; }
    else                  { s0 = SS * v[0][0]; s1 = SS * v[0][1]; }
    #pragma unroll
    for (int i = 1; i < SUB; ++i) {
        s0 = fmaf(AA, s0, SS * v[i][0]);
        s1 = fmaf(AA, s1, SS * v[i][1]);
    }
    f32x2 sv; sv[0] = s0; sv[1] = s1;
    lds[h][f2] = sv;
    __syncthreads();

    if (h == 0) {
        // compose chunk aggregate q and PUBLISH (before polling!)
        f32x2 a0 = lds[0][f2], a1 = lds[1][f2], a2 = lds[2][f2], a3 = lds[3][f2];
        f32x2 qv;
        qv[0] = fmaf(fmaf(fmaf(a0[0], P16, a1[0]), P16, a2[0]), P16, a3[0]);
        qv[1] = fmaf(fmaf(fmaf(a0[1], P16, a1[1]), P16, a2[1]), P16, a3[1]);
        *((f32x2*)(q + (size_t)bid * FF) + f2) = qv;
        __threadfence();                          // release: q visible at agent scope
        if (f2 == 0)
            __hip_atomic_store(&flags[bid], 1, __ATOMIC_RELAXED,
                               __HIP_MEMORY_SCOPE_AGENT);

        // poll predecessors: lane jj waits on flag[bid-1-jj]
        const int need = (k < WW) ? k : WW;
        bool pend = (f2 < need);
        while (__ballot(pend) != 0ull) {
            if (pend) {
                int fv = __hip_atomic_load(&flags[bid - 1 - f2], __ATOMIC_RELAXED,
                                           __HIP_MEMORY_SCOPE_AGENT);
                pend = (fv == 0);
            }
            if (__ballot(pend) != 0ull) __builtin_amdgcn_s_sleep(1);
        }
        __threadfence();                          // acquire: see published q rows

        float c0 = 0.0f, c1 = 0.0f;
        #pragma unroll
        for (int jj = 0; jj < WW; ++jj) {
            if (jj < need) {
                f32x2 qv2 = *((const f32x2*)(q + (size_t)(bid - 1 - jj) * FF) + f2);
                c0 = fmaf(WQ[jj], qv2[0], c0);
                c1 = fmaf(WQ[jj], qv2[1], c1);
            }
        }
        f32x2 cv; cv[0] = c0; cv[1] = c1;
        cs[f2] = cv;
    }
    __syncthreads();

    // M entering my sub-chunk: m = P16^h * carry + sum_{g<h} P16^(h-1-g) s_g
    f32x2 cv = cs[f2];
    float m0 = cv[0], m1 = cv[1];
    for (int g = 0; g < h; ++g) {        // h is wave-uniform
        f32x2 sg = lds[g][f2];
        m0 = fmaf(P16, m0, sg[0]);
        m1 = fmaf(P16, m1, sg[1]);
    }

    // exact EMA recurrence within my 16 steps + PCEN
    {
        f32x2 o;
        if (k == 0 && h == 0) { m0 = v[0][0]; m1 = v[0][1]; }
        else {
            m0 = fmaf(AA, m0, SS * v[0][0]);
            m1 = fmaf(AA, m1, SS * v[0][1]);
        }
        o[0] = pcen_out(v[0][0], m0);
        o[1] = pcen_out(v[0][1], m1);
        __builtin_nontemporal_store(o, op);
    }
    #pragma unroll
    for (int i = 1; i < SUB; ++i) {
        m0 = fmaf(AA, m0, SS * v[i][0]);
        m1 = fmaf(AA, m1, SS * v[i][1]);
        f32x2 o;
        o[0] = pcen_out(v[i][0], m0);
        o[1] = pcen_out(v[i][1], m1);
        __builtin_nontemporal_store(o, op + (size_t)i * (FF / 2));
    }
}

// ---- fallback (ws too small): R2-style warm-up kernel, known-good ----
__global__ __launch_bounds__(128) void pcen_fallback(const float* __restrict__ x,
                                                     float* __restrict__ out) {
    const int job = blockIdx.x;
    const int b   = job >> 5;
    const int k   = job & 31;
    const int f   = threadIdx.x;
    const int t0  = k * 256;
    const size_t base = ((size_t)b * TT + t0) * FF + f;
    const float* xp = x + base;
    float*       op = out + base;
    float m;
    if (k == 0) {
        float xv = xp[0];
        m = xv;
        op[0] = pcen_out(xv, m);
    } else {
        const float* wp = xp - (size_t)256 * FF;
        m = wp[0];
        #pragma unroll 8
        for (int j = 1; j < 256; ++j) m = fmaf(AA, m, SS * wp[(size_t)j * FF]);
        float xv = xp[0];
        m = fmaf(AA, m, SS * xv);
        op[0] = pcen_out(xv, m);
    }
    #pragma unroll 4
    for (int j = 1; j < 256; ++j) {
        float xv = xp[(size_t)j * FF];
        m = fmaf(AA, m, SS * xv);
        op[(size_t)j * FF] = pcen_out(xv, m);
    }
}

extern "C" void kernel_launch(void* const* d_in, const int* in_sizes, int n_in,
                              void* d_out, int out_size, void* d_ws, size_t ws_size,
                              hipStream_t stream) {
    const float* x = (const float*)d_in[0];
    float* out = (float*)d_out;
    (void)in_sizes; (void)n_in; (void)out_size;

    const size_t need = Q_OFF + (size_t)NBLK * FF * sizeof(float);  // ~2.06 MB
    if (ws_size >= need) {
        char* ws = (char*)d_ws;
        int*   flags  = (int*)ws;                    // [0, 16KB)
        int*   ticket = (int*)(ws + TICKET_OFF);     // one int
        float* q      = (float*)(ws + Q_OFF);        // 2 MB
        // reset flags + ticket every call (graph-capture-safe async memset)
        hipMemsetAsync(ws, 0, TICKET_OFF + 64, stream);
        pcen_onepass<<<NBLK, 256, 0, stream>>>(x, out, q, flags, ticket);
    } else {
        pcen_fallback<<<BB * 32, 128, 0, stream>>>(x, out);
    }
}

// Round 9
// 77.760 us; speedup vs baseline: 3.8174x; 3.8174x over previous
//
#include <hip/hip_runtime.h>
#include <math.h>

// PCEN: EMA over time (s=0.025) + (x/(M+eps)^0.98 + 2)^0.5 - 2^0.5
// x: [B=32, T=8192, F=128] f32 -> out same shape f32.
//
// R8 -> R9: single-pass chained scan, FENCE-FREE handoff.
// R8's failure: __threadfence() per block = L2 writeback on gfx950 (per-XCD
// L2 non-coherent) -> 4096 flushes -> 372 us. Fix: publish q via RELAXED
// AGENT-SCOPE ATOMIC stores (sc1, coherence-point ops, no flush); consumers
// poll with relaxed agent atomic loads until value != sentinel. The data is
// the flag: q >= 0 always, sentinel 0xFFFFFFFF (negative NaN) unreachable.
// Ticket from atomicAdd => predecessors always resident-or-retired =>
// deadlock-free under any dispatch order (G16-safe).
// Carry into chunk k = sum_{jj=1..6} a^(64 jj) ... a^384 ~ 6e-5 truncation
// (k<=6 exact). Floor: ~134 MB read (partly L3-resident across replays,
// thanks to nt out-stores) + 134 MB write.

#define BB 32
#define TT 8192
#define FF 128
#define CC 64            // chunk timesteps per block
#define KC (TT / CC)     // 128 chunks per chain
#define SUB 16           // timesteps per thread
#define NH  (CC / SUB)   // 4 sub-chunks (one per wave)
#define WW 6             // look-back window in chunks
#define AA 0.975f
#define SS 0.025f

#define NBLK (BB * KC)   // 4096
#define Q_OFF 4096       // q at ws+4KB (ticket in first 64 B)

using f32x2 = __attribute__((ext_vector_type(2))) float;

constexpr float powf_n(float a, int n) {
    float p = 1.0f;
    for (int i = 0; i < n; ++i) p *= a;
    return p;
}
constexpr float P16 = powf_n(0.975f, 16);   // sub-chunk multiplier
// carry = sum_{jj=0..W-1} P64^jj * q[k-1-jj]
constexpr float WQ[WW] = {
    powf_n(0.975f, 0),   powf_n(0.975f, 64),  powf_n(0.975f, 128),
    powf_n(0.975f, 192), powf_n(0.975f, 256), powf_n(0.975f, 320)
};

__device__ __forceinline__ float pcen_out(float xv, float m) {
    // (m+eps)^(-0.98) via v_log_f32 / v_exp_f32
    float p = __builtin_amdgcn_exp2f(-0.98f * __builtin_amdgcn_logf(m + 1e-6f));
    return sqrtf(fmaf(xv, p, 2.0f)) - 1.41421356237309505f;
}

__global__ __launch_bounds__(256) void pcen_onepass(const float* __restrict__ x,
                                                    float* __restrict__ out,
                                                    unsigned long long* __restrict__ q,
                                                    int* __restrict__ ticket) {
    __shared__ f32x2 lds[NH][64];
    __shared__ f32x2 cs[64];
    __shared__ int bid_s;

    const int tid = threadIdx.x;
    const int h   = tid >> 6;            // wave id / sub-chunk, 0..3
    const int f2  = tid & 63;

    if (tid == 0)
        bid_s = __hip_atomic_fetch_add(ticket, 1, __ATOMIC_RELAXED,
                                       __HIP_MEMORY_SCOPE_AGENT);
    __syncthreads();
    const int bid = bid_s;               // virtual block id = b*KC + k
    const int b   = bid >> 7;
    const int k   = bid & (KC - 1);

    const size_t tbase = (size_t)b * TT + (size_t)k * CC + (size_t)h * SUB;
    const f32x2* xp = (const f32x2*)(x + tbase * FF) + f2;
    f32x2*       op = (f32x2*)(out + tbase * FF) + f2;

    f32x2 v[SUB];
    #pragma unroll
    for (int i = 0; i < SUB; ++i) v[i] = xp[(size_t)i * (FF / 2)];

    // sub-aggregate: init-0 EMA over 16 steps (anchored for k==0,h==0)
    float s0, s1;
    if (k == 0 && h == 0) { s0 = v[0][0];      s1 = v[0][1]; }
    else                  { s0 = SS * v[0][0]; s1 = SS * v[0][1]; }
    #pragma unroll
    for (int i = 1; i < SUB; ++i) {
        s0 = fmaf(AA, s0, SS * v[i][0]);
        s1 = fmaf(AA, s1, SS * v[i][1]);
    }
    f32x2 sv; sv[0] = s0; sv[1] = s1;
    lds[h][f2] = sv;
    __syncthreads();

    if (h == 0) {
        // compose chunk aggregate q and PUBLISH via relaxed agent atomic
        // (single sc1 store at the coherence point -- no fence, no L2 flush)
        f32x2 a0 = lds[0][f2], a1 = lds[1][f2], a2 = lds[2][f2], a3 = lds[3][f2];
        union { f32x2 v; unsigned long long u; } pub;
        pub.v[0] = fmaf(fmaf(fmaf(a0[0], P16, a1[0]), P16, a2[0]), P16, a3[0]);
        pub.v[1] = fmaf(fmaf(fmaf(a0[1], P16, a1[1]), P16, a2[1]), P16, a3[1]);
        __hip_atomic_store(q + (size_t)bid * (FF / 2) + f2, pub.u,
                           __ATOMIC_RELAXED, __HIP_MEMORY_SCOPE_AGENT);

        // poll predecessors by VALUE (sentinel = 0xFFFFFFFF words; real q
        // is always >= 0 so the pattern is unreachable)
        const int need = (k < WW) ? k : WW;
        float c0 = 0.0f, c1 = 0.0f;
        #pragma unroll
        for (int jj = 0; jj < WW; ++jj) {
            if (jj < need) {
                const unsigned long long* qp =
                    q + (size_t)(bid - 1 - jj) * (FF / 2) + f2;
                union { unsigned long long u; f32x2 v; } got;
                for (;;) {
                    got.u = __hip_atomic_load(qp, __ATOMIC_RELAXED,
                                              __HIP_MEMORY_SCOPE_AGENT);
                    if ((unsigned)got.u != 0xFFFFFFFFu &&
                        (unsigned)(got.u >> 32) != 0xFFFFFFFFu) break;
                    __builtin_amdgcn_s_sleep(2);
                }
                c0 = fmaf(WQ[jj], got.v[0], c0);
                c1 = fmaf(WQ[jj], got.v[1], c1);
            }
        }
        f32x2 cv; cv[0] = c0; cv[1] = c1;
        cs[f2] = cv;
    }
    __syncthreads();

    // M entering my sub-chunk: m = P16^h * carry + sum_{g<h} P16^(h-1-g) s_g
    f32x2 cv = cs[f2];
    float m0 = cv[0], m1 = cv[1];
    for (int g = 0; g < h; ++g) {        // h is wave-uniform
        f32x2 sg = lds[g][f2];
        m0 = fmaf(P16, m0, sg[0]);
        m1 = fmaf(P16, m1, sg[1]);
    }

    // exact EMA recurrence within my 16 steps + PCEN
    {
        f32x2 o;
        if (k == 0 && h == 0) { m0 = v[0][0]; m1 = v[0][1]; }
        else {
            m0 = fmaf(AA, m0, SS * v[0][0]);
            m1 = fmaf(AA, m1, SS * v[0][1]);
        }
        o[0] = pcen_out(v[0][0], m0);
        o[1] = pcen_out(v[0][1], m1);
        __builtin_nontemporal_store(o, op);
    }
    #pragma unroll
    for (int i = 1; i < SUB; ++i) {
        m0 = fmaf(AA, m0, SS * v[i][0]);
        m1 = fmaf(AA, m1, SS * v[i][1]);
        f32x2 o;
        o[0] = pcen_out(v[i][0], m0);
        o[1] = pcen_out(v[i][1], m1);
        __builtin_nontemporal_store(o, op + (size_t)i * (FF / 2));
    }
}

// ---- fallback (ws too small): R2-style warm-up kernel, known-good ----
__global__ __launch_bounds__(128) void pcen_fallback(const float* __restrict__ x,
                                                     float* __restrict__ out) {
    const int job = blockIdx.x;
    const int b   = job >> 5;
    const int k   = job & 31;
    const int f   = threadIdx.x;
    const int t0  = k * 256;
    const size_t base = ((size_t)b * TT + t0) * FF + f;
    const float* xp = x + base;
    float*       op = out + base;
    float m;
    if (k == 0) {
        float xv = xp[0];
        m = xv;
        op[0] = pcen_out(xv, m);
    } else {
        const float* wp = xp - (size_t)256 * FF;
        m = wp[0];
        #pragma unroll 8
        for (int j = 1; j < 256; ++j) m = fmaf(AA, m, SS * wp[(size_t)j * FF]);
        float xv = xp[0];
        m = fmaf(AA, m, SS * xv);
        op[0] = pcen_out(xv, m);
    }
    #pragma unroll 4
    for (int j = 1; j < 256; ++j) {
        float xv = xp[(size_t)j * FF];
        m = fmaf(AA, m, SS * xv);
        op[(size_t)j * FF] = pcen_out(xv, m);
    }
}

extern "C" void kernel_launch(void* const* d_in, const int* in_sizes, int n_in,
                              void* d_out, int out_size, void* d_ws, size_t ws_size,
                              hipStream_t stream) {
    const float* x = (const float*)d_in[0];
    float* out = (float*)d_out;
    (void)in_sizes; (void)n_in; (void)out_size;

    const size_t q_bytes = (size_t)NBLK * FF * sizeof(float);       // 2 MB
    const size_t need    = Q_OFF + q_bytes;
    if (ws_size >= need) {
        char* ws = (char*)d_ws;
        int* ticket = (int*)ws;
        unsigned long long* q = (unsigned long long*)(ws + Q_OFF);
        // reset each call (graph-capture-safe async memsets):
        hipMemsetAsync(ws, 0, 64, stream);            // ticket = 0
        hipMemsetAsync(q, 0xFF, q_bytes, stream);     // q = sentinel (neg NaN)
        pcen_onepass<<<NBLK, 256, 0, stream>>>(x, out, q, ticket);
    } else {
        pcen_fallback<<<BB * 32, 128, 0, stream>>>(x, out);
    }
}